// Round 1
// baseline (214.928 us; speedup 1.0000x reference)
//
#include <hip/hip_runtime.h>
#include <math.h>

// Problem geometry (fixed by the reference)
#define NB 2
#define NVOICE 8
#define NN (NB * NVOICE)   // 16 series
#define NH 64              // harmonics
#define NF 500             // frames
#define NT 32000           // samples
#define NCHUNK 32          // angular_cumsum chunks of 1000
#define CHUNK 1000
#define NSUB 8             // sub-chunks per chunk for parallel re-walk
#define SUBLEN 125

// f32-rounded constants exactly as numpy/jax weak-promotion produces them
__device__ __constant__ float d_dummy; // (unused; keeps toolchain happy)

static __device__ __forceinline__ float tpi_f()  { return (float)(6.283185307179586); }
static __device__ __forceinline__ float omc_f()  { return (float)(6.283185307179586 / 16000.0); }

// Bit-exact replication of linear_resample'd harmonic frequency at sample t, harmonic h.
// t' = (t+0.5)*(500/32000) - 0.5 ; all intermediate values exactly representable in f32,
// so op fusion cannot change them. The lerp itself uses explicit rn intrinsics (no FMA).
static __device__ __forceinline__ float freq_env_exact(const float* __restrict__ fr, int t, int h) {
    float tp = ((float)t + 0.5f) * 0.015625f - 0.5f;   // exact
    tp = fminf(fmaxf(tp, 0.0f), 499.0f);
    int i0 = (int)tp;
    float w = tp - (float)i0;                           // exact
    int i1 = (i0 + 1 < NF) ? i0 + 1 : NF - 1;
    float kf = (float)(h + 1);
    float hf0 = __fmul_rn(fr[i0], kf);
    float hf1 = __fmul_rn(fr[i1], kf);
    return __fadd_rn(__fmul_rn(hf0, 1.0f - w), __fmul_rn(hf1, w));
}

// K1: frame-level harmonic amplitudes  ha[n][f][h]
__global__ __launch_bounds__(64) void k1_harm_amps(const float* __restrict__ freqs,
                                                   const float* __restrict__ harms,
                                                   const float* __restrict__ amps,
                                                   float* __restrict__ ha) {
    int blk = blockIdx.x;             // n*NF + f
    int n = blk / NF, f = blk % NF;
    int h = threadIdx.x;
    float freq = freqs[n * NF + f];
    float hm   = harms[(n * NH + h) * NF + f];          // (b,v,h,f) layout
    float hf   = __fmul_rn(freq, (float)(h + 1));
    float wv   = (hf > 8000.0f) ? 0.0f : hm;
    float den  = wv;
    #pragma unroll
    for (int m = 1; m < 64; m <<= 1) den += __shfl_xor(den, m, 64);
    float d2 = (den == 0.0f) ? 1e-7f : den;
    ha[(n * NF + f) * NH + h] = __fmul_rn(amps[n * NF + f], __fdiv_rn(wv, d2));
}

// K2: per-(n,h,chunk) sequential f32 omega scan (bit-exact cumsum).
// Stores sub-chunk boundary partial sums and the chunk total.
__global__ __launch_bounds__(64) void k2_chunk_scan(const float* __restrict__ freqs,
                                                    float* __restrict__ substart,
                                                    float* __restrict__ totals) {
    int blk = blockIdx.x;             // n*NCHUNK + c
    int n = blk / NCHUNK, c = blk % NCHUNK;
    int h = threadIdx.x;
    const float* fr = freqs + n * NF;
    float* sp = substart + (size_t)((n * NH + h) * NCHUNK + c) * NSUB;
    float s = 0.0f;
    for (int k = 0; k < CHUNK; ++k) {
        if ((k % SUBLEN) == 0) sp[k / SUBLEN] = s;     // exclusive partial at sub boundary
        int t = c * CHUNK + k;
        float fe = freq_env_exact(fr, t, h);
        float om = __fmul_rn(fe, omc_f());
        s = __fadd_rn(s, om);
    }
    totals[(n * NH + h) * NCHUNK + c] = s;
}

// K3: offsets chain — offsets = cumsum([0, fmod(total_c, 2pi)...]) % 2pi  (sequential f32)
__global__ __launch_bounds__(64) void k3_offsets(const float* __restrict__ totals,
                                                 float* __restrict__ offs) {
    int n = blockIdx.x;
    int h = threadIdx.x;
    const float* tt = totals + (n * NH + h) * NCHUNK;
    float* oo = offs + (n * NH + h) * NCHUNK;
    float cum = 0.0f;
    for (int c = 0; c < NCHUNK; ++c) {
        oo[c] = fmodf(cum, tpi_f());
        cum = __fadd_rn(cum, fmodf(tt[c], tpi_f()));
    }
}

// K4: synthesis. Block = (b, chunk, sub); 512 threads = 8 voices x 64 harmonics.
// Lane h resumes the bit-exact f32 scan from its sub-boundary partial.
__global__ __launch_bounds__(512) void k4_synth(const float* __restrict__ freqs,
                                                const float* __restrict__ ha,
                                                const float* __restrict__ substart,
                                                const float* __restrict__ offs,
                                                float* __restrict__ out) {
    int blk = blockIdx.x;             // b*(NCHUNK*NSUB) + c*NSUB + sub
    int b   = blk / (NCHUNK * NSUB);
    int rem = blk % (NCHUNK * NSUB);
    int c   = rem / NSUB, sub = rem % NSUB;
    int tid = threadIdx.x;
    int v = tid >> 6, h = tid & 63;
    int n = b * NVOICE + v;

    __shared__ float wA[64], wB[64];
    __shared__ float vsum[NVOICE][SUBLEN];
    if (tid < 64) {
        // win[j] = 0.5 - 0.5*cos(fl(2pi * j) / 128), numpy-faithful op order
        float a0 = __fmul_rn(tpi_f(), (float)tid) * 0.0078125f;        // /128 exact
        float a1 = __fmul_rn(tpi_f(), (float)(tid + 64)) * 0.0078125f;
        wA[tid] = 0.5f - 0.5f * cosf(a0);   // win[r]       -> weights frame p+1
        wB[tid] = 0.5f - 0.5f * cosf(a1);   // win[64+r]    -> weights frame p
    }
    __syncthreads();

    const float* fr  = freqs + n * NF;
    const float* han = ha + (size_t)n * NF * NH;
    float s   = substart[(size_t)((n * NH + h) * NCHUNK + c) * NSUB + sub];
    float off = offs[(n * NH + h) * NCHUNK + c];
    int t0 = c * CHUNK + sub * SUBLEN;

    for (int k = 0; k < SUBLEN; ++k) {
        int t = t0 + k;
        float fe = freq_env_exact(fr, t, h);
        float om = __fmul_rn(fe, omc_f());
        s = __fadd_rn(s, om);                              // inclusive cumsum value
        float ph = fmodf(__fadd_rn(s, off), tpi_f());
        float sv = sinf(ph);
        int p  = t >> 6, r = t & 63;
        int p1 = (p + 1 < NF) ? p + 1 : NF - 1;            // padded last frame
        float a0 = han[p * NH + h];
        float a1 = han[p1 * NH + h];
        float amp = __fadd_rn(__fmul_rn(a1, wA[r]), __fmul_rn(a0, wB[r]));
        amp = (fe > 8000.0f) ? 0.0f : amp;                 // strict >, bit-exact fe
        float contrib = __fmul_rn(sv, amp);
        #pragma unroll
        for (int m = 1; m < 64; m <<= 1) contrib += __shfl_xor(contrib, m, 64);
        if (h == 0) vsum[v][k] = contrib;
    }
    __syncthreads();

    if (tid < SUBLEN) {
        float acc = 0.0f;
        #pragma unroll
        for (int vv = 0; vv < NVOICE; ++vv) acc = __fadd_rn(acc, vsum[vv][tid]);
        out[b * NT + t0 + tid] = __fmul_rn(0.02f, acc);
    }
}

extern "C" void kernel_launch(void* const* d_in, const int* in_sizes, int n_in,
                              void* d_out, int out_size, void* d_ws, size_t ws_size,
                              hipStream_t stream) {
    (void)in_sizes; (void)n_in; (void)out_size; (void)ws_size;
    const float* freqs = (const float*)d_in[0];   // (2,8,500)
    const float* harms = (const float*)d_in[1];   // (2,8,64,500)
    const float* amps  = (const float*)d_in[2];   // (2,8,500)
    float* out = (float*)d_out;                   // (2,32000)

    // Workspace partition (floats)
    float* ws = (float*)d_ws;
    float* ha       = ws;                                   // 16*500*64      = 512000
    float* substart = ha + (size_t)NN * NF * NH;            // 16*64*32*8     = 262144
    float* totals   = substart + (size_t)NN * NH * NCHUNK * NSUB; // 32768
    float* offs     = totals + (size_t)NN * NH * NCHUNK;    // 32768

    hipLaunchKernelGGL(k1_harm_amps, dim3(NN * NF), dim3(64), 0, stream,
                       freqs, harms, amps, ha);
    hipLaunchKernelGGL(k2_chunk_scan, dim3(NN * NCHUNK), dim3(64), 0, stream,
                       freqs, substart, totals);
    hipLaunchKernelGGL(k3_offsets, dim3(NN), dim3(64), 0, stream,
                       totals, offs);
    hipLaunchKernelGGL(k4_synth, dim3(NB * NCHUNK * NSUB), dim3(512), 0, stream,
                       freqs, ha, substart, offs, out);
}

// Round 2
// 136.819 us; speedup vs baseline: 1.5709x; 1.5709x over previous
//
#include <hip/hip_runtime.h>
#include <math.h>

// Problem geometry (fixed by the reference)
#define NB 2
#define NVOICE 8
#define NN (NB * NVOICE)   // 16 series
#define NH 64              // harmonics
#define NF 500             // frames
#define NT 32000           // samples
#define NCHUNK 32          // angular_cumsum chunks of 1000
#define CHUNK 1000
#define NSUB 8             // sub-chunks per chunk for parallel re-walk
#define SUBLEN 125

static __device__ __forceinline__ float tpi_f()    { return (float)(6.283185307179586); }
static __device__ __forceinline__ float omc_f()    { return (float)(6.283185307179586 / 16000.0); }
static __device__ __forceinline__ float inv2pi_f() { return (float)(1.0 / 6.283185307179586); }

// K1: frame-level harmonic amplitudes  ha[n][f][h]
__global__ __launch_bounds__(64) void k1_harm_amps(const float* __restrict__ freqs,
                                                   const float* __restrict__ harms,
                                                   const float* __restrict__ amps,
                                                   float* __restrict__ ha) {
    int blk = blockIdx.x;             // n*NF + f
    int n = blk / NF, f = blk % NF;
    int h = threadIdx.x;
    float freq = freqs[n * NF + f];
    float hm   = harms[(n * NH + h) * NF + f];          // (b,v,h,f) layout
    float hf   = __fmul_rn(freq, (float)(h + 1));
    float wv   = (hf > 8000.0f) ? 0.0f : hm;
    float den  = wv;
    #pragma unroll
    for (int m = 1; m < 64; m <<= 1) den += __shfl_xor(den, m, 64);
    float d2 = (den == 0.0f) ? 1e-7f : den;
    ha[(n * NF + f) * NH + h] = __fmul_rn(amps[n * NF + f], __fdiv_rn(wv, d2));
}

// K2: per-(n,h,chunk) sequential f32 omega scan (bit-exact cumsum).
// Segment-hoisted frequency lerp: i0 changes only at t == 32 (mod 64); the
// incremental w += 1/64 is exact (all values dyadic multiples of 2^-7).
__global__ __launch_bounds__(64) void k2_chunk_scan(const float* __restrict__ freqs,
                                                    float* __restrict__ substart,
                                                    float* __restrict__ totals) {
    int blk = blockIdx.x;             // n*NCHUNK + c
    int n = blk / NCHUNK, c = blk % NCHUNK;
    int h = threadIdx.x;
    __shared__ float sfr[NF];
    for (int i = h; i < NF; i += 64) sfr[i] = freqs[n * NF + i];
    __syncthreads();

    const float kf = (float)(h + 1);
    int t0 = c * CHUNK;
    float tp = ((float)t0 + 0.5f) * 0.015625f - 0.5f;   // exact
    tp = fminf(fmaxf(tp, 0.0f), 499.0f);
    int i0 = (int)tp;
    float w = tp - (float)i0;                            // exact
    int i1 = (i0 + 1 < NF) ? i0 + 1 : NF - 1;
    float hf0 = __fmul_rn(sfr[i0], kf), hf1 = __fmul_rn(sfr[i1], kf);

    float s = 0.0f;
    int t = t0;
    for (int sub = 0; sub < NSUB; ++sub) {
        substart[(((size_t)c * NSUB + sub) * NN + n) * NH + h] = s;  // exclusive prefix
        for (int j = 0; j < SUBLEN; ++j) {
            float fe = __fadd_rn(__fmul_rn(hf0, 1.0f - w), __fmul_rn(hf1, w));
            s = __fadd_rn(s, __fmul_rn(fe, omc_f()));
            ++t;
            if (t <= 32 || t >= NT - 32) {               // clipped edge regions: recompute exactly
                float tq = ((float)t + 0.5f) * 0.015625f - 0.5f;
                tq = fminf(fmaxf(tq, 0.0f), 499.0f);
                int ni = (int)tq; w = tq - (float)ni;
                if (ni != i0) { i0 = ni; i1 = (i0 + 1 < NF) ? i0 + 1 : NF - 1;
                                hf0 = __fmul_rn(sfr[i0], kf); hf1 = __fmul_rn(sfr[i1], kf); }
            } else {
                w = __fadd_rn(w, 0.015625f);             // exact
                if (w >= 1.0f) {
                    w = __fadd_rn(w, -1.0f);             // exact
                    ++i0; i1 = (i0 + 1 < NF) ? i0 + 1 : NF - 1;
                    hf0 = __fmul_rn(sfr[i0], kf); hf1 = __fmul_rn(sfr[i1], kf);
                }
            }
        }
    }
    totals[((size_t)c * NN + n) * NH + h] = s;
}

// K3: offsets chain — sequential f32, coalesced [c][n][h] layout
__global__ __launch_bounds__(64) void k3_offsets(const float* __restrict__ totals,
                                                 float* __restrict__ offs) {
    int n = blockIdx.x;
    int h = threadIdx.x;
    float cum = 0.0f;
    for (int c = 0; c < NCHUNK; ++c) {
        offs[((size_t)c * NN + n) * NH + h] = fmodf(cum, tpi_f());
        cum = __fadd_rn(cum, fmodf(totals[((size_t)c * NN + n) * NH + h], tpi_f()));
    }
}

// K4: synthesis. Block = (b, chunk, sub); 512 threads = 8 voices x 64 harmonics.
__global__ __launch_bounds__(512) void k4_synth(const float* __restrict__ freqs,
                                                const float* __restrict__ ha,
                                                const float* __restrict__ substart,
                                                const float* __restrict__ offs,
                                                float* __restrict__ out) {
    int blk = blockIdx.x;             // b*(NCHUNK*NSUB) + c*NSUB + sub
    int b   = blk / (NCHUNK * NSUB);
    int rem = blk % (NCHUNK * NSUB);
    int c   = rem / NSUB, sub = rem % NSUB;
    int tid = threadIdx.x;
    int v = tid >> 6, h = tid & 63;
    int n = b * NVOICE + v;

    __shared__ float2 wAB[64];                 // x = win[r] (frame p+1), y = win[64+r] (frame p)
    __shared__ float vsum[NVOICE][SUBLEN];
    if (tid < 64) {
        float a0 = __fmul_rn(tpi_f(), (float)tid) * 0.0078125f;
        float a1 = __fmul_rn(tpi_f(), (float)(tid + 64)) * 0.0078125f;
        wAB[tid] = make_float2(0.5f - 0.5f * cosf(a0), 0.5f - 0.5f * cosf(a1));
    }
    __syncthreads();

    const float kf = (float)(h + 1);
    const float* __restrict__ fr  = freqs + n * NF;
    const float* __restrict__ han = ha + (size_t)n * NF * NH;
    int t0 = c * CHUNK + sub * SUBLEN;
    float s   = substart[(((size_t)c * NSUB + sub) * NN + n) * NH + h];
    float off = offs[((size_t)c * NN + n) * NH + h];
    float off_rev = __fmul_rn(off, inv2pi_f());

    // init freq-lerp segment state
    float tp = ((float)t0 + 0.5f) * 0.015625f - 0.5f;
    tp = fminf(fmaxf(tp, 0.0f), 499.0f);
    int i0 = (int)tp; float w = tp - (float)i0;
    int i1 = (i0 + 1 < NF) ? i0 + 1 : NF - 1;
    float hf0 = __fmul_rn(fr[i0], kf), hf1 = __fmul_rn(fr[i1], kf);
    // init amp-window segment state
    int p = t0 >> 6, r = t0 & 63;
    int p1 = (p + 1 < NF) ? p + 1 : NF - 1;
    float a0 = han[p * NH + h], a1 = han[p1 * NH + h];

    int t = t0;
    for (int k = 0; k < SUBLEN; ++k) {
        float fe = __fadd_rn(__fmul_rn(hf0, 1.0f - w), __fmul_rn(hf1, w));
        s = __fadd_rn(s, __fmul_rn(fe, omc_f()));        // inclusive cumsum value
        float pr = __fmaf_rn(s, inv2pi_f(), off_rev);    // phase in revolutions
        float fr_, sv;
        asm("v_fract_f32 %0, %1" : "=v"(fr_) : "v"(pr));
        asm("v_sin_f32 %0, %1" : "=v"(sv) : "v"(fr_));   // sin(2*pi*frac)
        float2 wab = wAB[r];
        float amp = __fadd_rn(__fmul_rn(a1, wab.x), __fmul_rn(a0, wab.y));
        amp = (fe > 8000.0f) ? 0.0f : amp;               // strict >, bit-exact fe
        float contrib = __fmul_rn(sv, amp);
        #pragma unroll
        for (int m = 1; m < 64; m <<= 1) contrib += __shfl_xor(contrib, m, 64);
        if (h == 0) vsum[v][k] = contrib;
        // ---- advance to t+1 ----
        ++t;
        ++r;
        if (r == 64) {
            r = 0; p = t >> 6; p1 = (p + 1 < NF) ? p + 1 : NF - 1;
            a0 = han[p * NH + h]; a1 = han[p1 * NH + h];
        }
        if (t <= 32 || t >= NT - 32) {
            float tq = ((float)t + 0.5f) * 0.015625f - 0.5f;
            tq = fminf(fmaxf(tq, 0.0f), 499.0f);
            int ni = (int)tq; w = tq - (float)ni;
            if (ni != i0) { i0 = ni; i1 = (i0 + 1 < NF) ? i0 + 1 : NF - 1;
                            hf0 = __fmul_rn(fr[i0], kf); hf1 = __fmul_rn(fr[i1], kf); }
        } else {
            w = __fadd_rn(w, 0.015625f);
            if (w >= 1.0f) {
                w = __fadd_rn(w, -1.0f);
                ++i0; i1 = (i0 + 1 < NF) ? i0 + 1 : NF - 1;
                hf0 = __fmul_rn(fr[i0], kf); hf1 = __fmul_rn(fr[i1], kf);
            }
        }
    }
    __syncthreads();

    if (tid < SUBLEN) {
        float acc = 0.0f;
        #pragma unroll
        for (int vv = 0; vv < NVOICE; ++vv) acc = __fadd_rn(acc, vsum[vv][tid]);
        out[b * NT + c * CHUNK + sub * SUBLEN + tid] = __fmul_rn(0.02f, acc);
    }
}

extern "C" void kernel_launch(void* const* d_in, const int* in_sizes, int n_in,
                              void* d_out, int out_size, void* d_ws, size_t ws_size,
                              hipStream_t stream) {
    (void)in_sizes; (void)n_in; (void)out_size; (void)ws_size;
    const float* freqs = (const float*)d_in[0];   // (2,8,500)
    const float* harms = (const float*)d_in[1];   // (2,8,64,500)
    const float* amps  = (const float*)d_in[2];   // (2,8,500)
    float* out = (float*)d_out;                   // (2,32000)

    // Workspace partition (floats)
    float* ws = (float*)d_ws;
    float* ha       = ws;                                   // 16*500*64      = 512000
    float* substart = ha + (size_t)NN * NF * NH;            // 32*8*16*64     = 262144
    float* totals   = substart + (size_t)NCHUNK * NSUB * NN * NH; // 32*16*64 = 32768
    float* offs     = totals + (size_t)NCHUNK * NN * NH;    // 32768

    hipLaunchKernelGGL(k1_harm_amps, dim3(NN * NF), dim3(64), 0, stream,
                       freqs, harms, amps, ha);
    hipLaunchKernelGGL(k2_chunk_scan, dim3(NN * NCHUNK), dim3(64), 0, stream,
                       freqs, substart, totals);
    hipLaunchKernelGGL(k3_offsets, dim3(NN), dim3(64), 0, stream,
                       totals, offs);
    hipLaunchKernelGGL(k4_synth, dim3(NB * NCHUNK * NSUB), dim3(512), 0, stream,
                       freqs, ha, substart, offs, out);
}

// Round 3
// 108.744 us; speedup vs baseline: 1.9764x; 1.2582x over previous
//
#include <hip/hip_runtime.h>
#include <math.h>

// Problem geometry (fixed by the reference)
#define NB 2
#define NVOICE 8
#define NN (NB * NVOICE)   // 16 series
#define NH 64              // harmonics
#define NF 500             // frames
#define NT 32000           // samples
#define NCHUNK 32          // angular_cumsum chunks of 1000
#define CHUNK 1000
#define NSUB 8             // sub-chunks per chunk for parallel re-walk
#define SUBLEN 125

static __device__ __forceinline__ float tpi_f()    { return (float)(6.283185307179586); }
static __device__ __forceinline__ float omc_f()    { return (float)(6.283185307179586 / 16000.0); }
static __device__ __forceinline__ float inv2pi_f() { return (float)(1.0 / 6.283185307179586); }

// Pure-VALU 64-lane sum via DPP butterfly; full sum lands on lane 63.
template<int CTRL>
static __device__ __forceinline__ float dpp_add(float x) {
    int y = __builtin_amdgcn_update_dpp(0, __float_as_int(x), CTRL, 0xF, 0xF, true);
    return x + __int_as_float(y);
}
static __device__ __forceinline__ float wave_sum_to63(float x) {
    x = dpp_add<0xB1>(x);    // quad_perm [1,0,3,2]  (xor 1)
    x = dpp_add<0x4E>(x);    // quad_perm [2,3,0,1]  (xor 2)
    x = dpp_add<0x141>(x);   // row_half_mirror      (8-groups)
    x = dpp_add<0x140>(x);   // row_mirror           (rows of 16)
    x = dpp_add<0x142>(x);   // row_bcast15          (rows 0+1, 2+3)
    x = dpp_add<0x143>(x);   // row_bcast31          (all 64 on upper lanes)
    return x;                // lane 63 holds the total
}

// K1: frame-level harmonic amplitudes, ha layout [n][h][f] (coalesced in f)
__global__ __launch_bounds__(256) void k1_harm_amps(const float* __restrict__ freqs,
                                                    const float* __restrict__ harms,
                                                    const float* __restrict__ amps,
                                                    float* __restrict__ ha) {
    int n = blockIdx.x >> 1;
    int f = ((blockIdx.x & 1) << 8) + threadIdx.x;
    if (f >= NF) return;
    float freq = freqs[n * NF + f];
    float av   = amps[n * NF + f];
    const float* __restrict__ hb = harms + (size_t)n * NH * NF + f;
    float den = 0.0f;
    #pragma unroll 8
    for (int h2 = 0; h2 < NH; ++h2) {
        float hm = hb[(size_t)h2 * NF];
        float hf = __fmul_rn(freq, (float)(h2 + 1));
        den = __fadd_rn(den, (hf > 8000.0f) ? 0.0f : hm);
    }
    float d2 = (den == 0.0f) ? 1e-7f : den;
    float* __restrict__ ob = ha + (size_t)n * NH * NF + f;
    #pragma unroll 8
    for (int h2 = 0; h2 < NH; ++h2) {
        float hm = hb[(size_t)h2 * NF];
        float hf = __fmul_rn(freq, (float)(h2 + 1));
        float wv = (hf > 8000.0f) ? 0.0f : hm;
        ob[(size_t)h2 * NF] = __fmul_rn(av, __fdiv_rn(wv, d2));
    }
}

// K2: bit-exact f32 omega scan per (n,h,c). w from LDS table (exact dyadics),
// hf0/hf1 in registers reloaded at wave-uniform segment boundaries.
__global__ __launch_bounds__(64) void k2_chunk_scan(const float* __restrict__ freqs,
                                                    float* __restrict__ substart,
                                                    float* __restrict__ tmod) {
    int blk = blockIdx.x;             // n*NCHUNK + c
    int n = blk >> 5, c = blk & 31;
    int h = threadIdx.x;
    __shared__ float2 wtab[64];       // {1-w, w} for r = t & 63 (valid for 32 <= t < NT-32)
    {
        int r = h;
        int m = (r >= 32) ? (2 * r - 63) : (2 * r + 65);
        float w = (float)m * 0.0078125f;                 // exact
        wtab[r] = make_float2(1.0f - w, w);
    }
    __syncthreads();

    const float kf = (float)(h + 1);
    const float* __restrict__ fr = freqs + n * NF;
    int t = c * CHUNK;
    int i0 = (t >= 32) ? ((t - 32) >> 6) : 0; if (i0 > NF - 1) i0 = NF - 1;
    int i1 = (i0 + 1 < NF) ? i0 + 1 : NF - 1;
    float hf0 = __fmul_rn(fr[i0], kf), hf1 = __fmul_rn(fr[i1], kf);

    float s = 0.0f;
    for (int sub = 0; sub < NSUB; ++sub) {
        substart[(((size_t)c * NSUB + sub) * NN + n) * NH + h] = s;   // exclusive prefix
        bool edge = (c == 0 && sub == 0) || (c == NCHUNK - 1 && sub == NSUB - 1);
        if (!edge) {
            #pragma unroll 5
            for (int k = 0; k < SUBLEN; ++k) {
                float2 wv = wtab[t & 63];
                float fe = __fadd_rn(__fmul_rn(hf0, wv.x), __fmul_rn(hf1, wv.y));
                s = __fadd_rn(s, __fmul_rn(fe, omc_f()));
                ++t;
                if ((t & 63) == 32) {
                    i0 = (t - 32) >> 6; if (i0 > NF - 1) i0 = NF - 1;
                    i1 = (i0 + 1 < NF) ? i0 + 1 : NF - 1;
                    hf0 = __fmul_rn(fr[i0], kf); hf1 = __fmul_rn(fr[i1], kf);
                }
            }
        } else {
            for (int k = 0; k < SUBLEN; ++k) {
                float tp = ((float)t + 0.5f) * 0.015625f - 0.5f;     // exact
                tp = fminf(fmaxf(tp, 0.0f), 499.0f);
                int e0 = (int)tp; float w = tp - (float)e0;          // exact
                int e1 = (e0 + 1 < NF) ? e0 + 1 : NF - 1;
                float fe = __fadd_rn(__fmul_rn(__fmul_rn(fr[e0], kf), 1.0f - w),
                                     __fmul_rn(__fmul_rn(fr[e1], kf), w));
                s = __fadd_rn(s, __fmul_rn(fe, omc_f()));
                ++t;
                if ((t & 63) == 32) {                                // keep state in sync
                    i0 = (t - 32) >> 6; if (i0 > NF - 1) i0 = NF - 1;
                    i1 = (i0 + 1 < NF) ? i0 + 1 : NF - 1;
                    hf0 = __fmul_rn(fr[i0], kf); hf1 = __fmul_rn(fr[i1], kf);
                }
            }
        }
    }
    tmod[((size_t)c * NN + n) * NH + h] = fmodf(s, tpi_f());
}

// K3: offsets chain — sequential f32 over chunks, coalesced [c][n][h] layout
__global__ __launch_bounds__(64) void k3_offsets(const float* __restrict__ tmod,
                                                 float* __restrict__ offs) {
    int n = blockIdx.x;
    int h = threadIdx.x;
    float cum = 0.0f;
    for (int c = 0; c < NCHUNK; ++c) {
        offs[((size_t)c * NN + n) * NH + h] = fmodf(cum, tpi_f());
        cum = __fadd_rn(cum, tmod[((size_t)c * NN + n) * NH + h]);
    }
}

// K4: synthesis. Block = (b, chunk, sub); 512 threads = 8 voices x 64 harmonics.
__global__ __launch_bounds__(512) void k4_synth(const float* __restrict__ freqs,
                                                const float* __restrict__ ha,
                                                const float* __restrict__ substart,
                                                const float* __restrict__ offs,
                                                float* __restrict__ out) {
    int blk = blockIdx.x;             // b*256 + c*8 + sub
    int b   = blk >> 8;
    int rem = blk & 255;
    int c   = rem >> 3, sub = rem & 7;
    int tid = threadIdx.x;
    int v = tid >> 6, h = tid & 63;
    int n = (b << 3) + v;

    __shared__ float4 tab[64];        // {1-w, w, win[r], win[64+r]}
    __shared__ float vsum[NVOICE][SUBLEN];
    if (tid < 64) {
        int r = tid;
        int m = (r >= 32) ? (2 * r - 63) : (2 * r + 65);
        float w  = (float)m * 0.0078125f;
        float aA = __fmul_rn(tpi_f(), (float)r) * 0.0078125f;
        float aB = __fmul_rn(tpi_f(), (float)(r + 64)) * 0.0078125f;
        tab[r] = make_float4(1.0f - w, w, 0.5f - 0.5f * cosf(aA), 0.5f - 0.5f * cosf(aB));
    }
    __syncthreads();

    const float kf = (float)(h + 1);
    const float* __restrict__ fr  = freqs + n * NF;
    const float* __restrict__ han = ha + ((size_t)n * NH + h) * NF;   // [n][h][f]
    int t0 = c * CHUNK + sub * SUBLEN;
    float s       = substart[(((size_t)c * NSUB + sub) * NN + n) * NH + h];
    float off_rev = __fmul_rn(offs[((size_t)c * NN + n) * NH + h], inv2pi_f());

    // freq-lerp segment state
    int i0 = (t0 >= 32) ? ((t0 - 32) >> 6) : 0; if (i0 > NF - 1) i0 = NF - 1;
    int i1 = (i0 + 1 < NF) ? i0 + 1 : NF - 1;
    float hf0 = __fmul_rn(fr[i0], kf), hf1 = __fmul_rn(fr[i1], kf);
    // amp frame state
    int p = t0 >> 6; if (p > NF - 1) p = NF - 1;
    int p1 = (p + 1 < NF) ? p + 1 : NF - 1;
    float a0 = han[p], a1 = han[p1];

    int t = t0;
    bool edge = (c == 0 && sub == 0) || (c == NCHUNK - 1 && sub == NSUB - 1);

    if (!edge) {
        #pragma unroll 5
        for (int k = 0; k < SUBLEN; ++k) {
            float4 tb = tab[t & 63];
            float fe = __fadd_rn(__fmul_rn(hf0, tb.x), __fmul_rn(hf1, tb.y));
            s = __fadd_rn(s, __fmul_rn(fe, omc_f()));
            float pr = __fmaf_rn(s, inv2pi_f(), off_rev);
            float fr_, sv;
            asm("v_fract_f32 %0, %1" : "=v"(fr_) : "v"(pr));
            asm("v_sin_f32 %0, %1" : "=v"(sv) : "v"(fr_));
            float amp = __fadd_rn(__fmul_rn(a1, tb.z), __fmul_rn(a0, tb.w));
            amp = (fe > 8000.0f) ? 0.0f : amp;
            float ct = wave_sum_to63(__fmul_rn(sv, amp));
            if (h == 63) vsum[v][k] = ct;
            ++t;
            if ((t & 63) == 0) {
                p = t >> 6; if (p > NF - 1) p = NF - 1;
                p1 = (p + 1 < NF) ? p + 1 : NF - 1;
                a0 = han[p]; a1 = han[p1];
            }
            if ((t & 63) == 32) {
                i0 = (t - 32) >> 6; if (i0 > NF - 1) i0 = NF - 1;
                i1 = (i0 + 1 < NF) ? i0 + 1 : NF - 1;
                hf0 = __fmul_rn(fr[i0], kf); hf1 = __fmul_rn(fr[i1], kf);
            }
        }
    } else {
        for (int k = 0; k < SUBLEN; ++k) {
            float4 tb = tab[t & 63];
            float tp = ((float)t + 0.5f) * 0.015625f - 0.5f;
            tp = fminf(fmaxf(tp, 0.0f), 499.0f);
            int e0 = (int)tp; float w = tp - (float)e0;
            int e1 = (e0 + 1 < NF) ? e0 + 1 : NF - 1;
            float fe = __fadd_rn(__fmul_rn(__fmul_rn(fr[e0], kf), 1.0f - w),
                                 __fmul_rn(__fmul_rn(fr[e1], kf), w));
            s = __fadd_rn(s, __fmul_rn(fe, omc_f()));
            float pr = __fmaf_rn(s, inv2pi_f(), off_rev);
            float fr_, sv;
            asm("v_fract_f32 %0, %1" : "=v"(fr_) : "v"(pr));
            asm("v_sin_f32 %0, %1" : "=v"(sv) : "v"(fr_));
            float amp = __fadd_rn(__fmul_rn(a1, tb.z), __fmul_rn(a0, tb.w));
            amp = (fe > 8000.0f) ? 0.0f : amp;
            float ct = wave_sum_to63(__fmul_rn(sv, amp));
            if (h == 63) vsum[v][k] = ct;
            ++t;
            if ((t & 63) == 0) {
                p = t >> 6; if (p > NF - 1) p = NF - 1;
                p1 = (p + 1 < NF) ? p + 1 : NF - 1;
                a0 = han[p]; a1 = han[p1];
            }
        }
    }
    __syncthreads();

    if (tid < SUBLEN) {
        float acc = 0.0f;
        #pragma unroll
        for (int vv = 0; vv < NVOICE; ++vv) acc = __fadd_rn(acc, vsum[vv][tid]);
        out[(size_t)b * NT + c * CHUNK + sub * SUBLEN + tid] = __fmul_rn(0.02f, acc);
    }
}

extern "C" void kernel_launch(void* const* d_in, const int* in_sizes, int n_in,
                              void* d_out, int out_size, void* d_ws, size_t ws_size,
                              hipStream_t stream) {
    (void)in_sizes; (void)n_in; (void)out_size; (void)ws_size;
    const float* freqs = (const float*)d_in[0];   // (2,8,500)
    const float* harms = (const float*)d_in[1];   // (2,8,64,500)
    const float* amps  = (const float*)d_in[2];   // (2,8,500)
    float* out = (float*)d_out;                   // (2,32000)

    // Workspace partition (floats) — same footprint as round 1 (3.36 MB)
    float* ws = (float*)d_ws;
    float* ha       = ws;                                        // 16*64*500 = 512000
    float* substart = ha + (size_t)NN * NH * NF;                 // 32*8*16*64 = 262144
    float* tmod     = substart + (size_t)NCHUNK * NSUB * NN * NH;// 32*16*64  = 32768
    float* offs     = tmod + (size_t)NCHUNK * NN * NH;           // 32768

    hipLaunchKernelGGL(k1_harm_amps, dim3(NN * 2), dim3(256), 0, stream,
                       freqs, harms, amps, ha);
    hipLaunchKernelGGL(k2_chunk_scan, dim3(NN * NCHUNK), dim3(64), 0, stream,
                       freqs, substart, tmod);
    hipLaunchKernelGGL(k3_offsets, dim3(NN), dim3(64), 0, stream,
                       tmod, offs);
    hipLaunchKernelGGL(k4_synth, dim3(NB * NCHUNK * NSUB), dim3(512), 0, stream,
                       freqs, ha, substart, offs, out);
}

// Round 4
// 62.174 us; speedup vs baseline: 3.4568x; 1.7490x over previous
//
#include <hip/hip_runtime.h>
#include <math.h>

// Problem geometry (fixed by the reference)
#define NB 2
#define NVOICE 8
#define NN (NB * NVOICE)   // 16 series
#define NH 64              // harmonics
#define NF 500             // frames
#define NT 32000           // samples
#define NCHUNK 32          // angular_cumsum chunks of 1000
#define CHUNK 1000
#define NPIECE 250         // 128-sample output pieces
#define PIECE 128

static __device__ __forceinline__ float tpi_f()    { return (float)(6.283185307179586); }
static __device__ __forceinline__ float omc_f()    { return (float)(6.283185307179586 / 16000.0); }
static __device__ __forceinline__ float inv2pi_f() { return (float)(1.0 / 6.283185307179586); }

// Pure-VALU 64-lane sum via DPP butterfly; full sum lands on lane 63.
template<int CTRL>
static __device__ __forceinline__ float dpp_add(float x) {
    int y = __builtin_amdgcn_update_dpp(0, __float_as_int(x), CTRL, 0xF, 0xF, true);
    return x + __int_as_float(y);
}
static __device__ __forceinline__ float wave_sum_to63(float x) {
    x = dpp_add<0xB1>(x);    // quad_perm xor1
    x = dpp_add<0x4E>(x);    // quad_perm xor2
    x = dpp_add<0x141>(x);   // row_half_mirror
    x = dpp_add<0x140>(x);   // row_mirror
    x = dpp_add<0x142>(x);   // row_bcast15
    x = dpp_add<0x143>(x);   // row_bcast31
    return x;                // lane 63 holds the total
}

// K1: frame-level harmonic amplitudes, ha layout [n][h][f]; single global pass.
__global__ __launch_bounds__(256) void k1_harm_amps(const float* __restrict__ freqs,
                                                    const float* __restrict__ harms,
                                                    const float* __restrict__ amps,
                                                    float* __restrict__ ha) {
    int n = blockIdx.x >> 1;
    int f = ((blockIdx.x & 1) << 8) + threadIdx.x;
    if (f >= NF) return;
    float freq = freqs[n * NF + f];
    float av   = amps[n * NF + f];
    const float* __restrict__ hb = harms + (size_t)n * NH * NF + f;
    float hmv[NH];
    float den = 0.0f;
    #pragma unroll
    for (int h2 = 0; h2 < NH; ++h2) {
        float hm = hb[(size_t)h2 * NF];
        float hf = __fmul_rn(freq, (float)(h2 + 1));
        hm = (hf > 8000.0f) ? 0.0f : hm;
        hmv[h2] = hm;
        den = __fadd_rn(den, hm);
    }
    float d2 = (den == 0.0f) ? 1e-7f : den;
    float* __restrict__ ob = ha + (size_t)n * NH * NF + f;
    #pragma unroll
    for (int h2 = 0; h2 < NH; ++h2)
        ob[(size_t)h2 * NF] = __fmul_rn(av, __fdiv_rn(hmv[h2], d2));
}

// ---- 64-sample window bodies: branch-free, all per-R constants folded ----
// Window q covers t = 64q + R.  R<32: lerp pair (q-1,q), wy=(2R+65)/128;
// R>=32: pair (q,q+1), wy=(2R-63)/128.  SP=1: q==0 (first half fe=fB exact);
// SP=2: q==NF-1 (second half fe=fB exact).  All dyadic weights exact.

template<bool MASKED, int SP>
static __device__ __forceinline__ void k2_window(float fA, float fB, float fC,
                                                 float& s, int lo, int hi) {
    #pragma unroll
    for (int R = 0; R < 64; ++R) {
        float wy = (float)((R < 32) ? (2 * R + 65) : (2 * R - 63)) * 0.0078125f;
        float wx = 1.0f - wy;
        float h0 = (R < 32) ? fA : fB;
        float h1 = (R < 32) ? fB : fC;
        float fe;
        if (SP == 1 && R < 32)       fe = fB;
        else if (SP == 2 && R >= 32) fe = fB;
        else fe = __fadd_rn(__fmul_rn(h0, wx), __fmul_rn(h1, wy));
        float om = __fmul_rn(fe, omc_f());
        if (MASKED) om = (R >= lo && R < hi) ? om : 0.0f;   // fadd(s,+0)=s exact
        s = __fadd_rn(s, om);
    }
}

// K2: bit-exact f32 omega scan per (n,c); stores exclusive prefix s at every
// 128-aligned t (piece starts) and the chunk total mod 2pi.
__global__ __launch_bounds__(64) void k2_chunk_scan(const float* __restrict__ freqs,
                                                    float* __restrict__ substart,
                                                    float* __restrict__ tmod) {
    int n = blockIdx.x >> 5, c = blockIdx.x & 31;
    int h = threadIdx.x;
    const float kf = (float)(h + 1);
    const float* __restrict__ fr = freqs + n * NF;
    const int tbeg = c * CHUNK, tend = tbeg + CHUNK;
    int t = tbeg & ~63;
    int q = t >> 6;
    float vA = fr[(q > 0) ? q - 1 : 0];
    float vB = fr[q];
    float vC = fr[(q + 1 < NF) ? q + 1 : NF - 1];
    float s = 0.0f;
    while (t < tend) {
        q = t >> 6;
        float vNext = fr[(q + 2 < NF) ? q + 2 : NF - 1];    // prefetch next window
        if ((t & 127) == 0 && t >= tbeg)
            substart[(((size_t)(t >> 7)) * NN + n) * NH + h] = s;
        float fA = __fmul_rn(vA, kf), fB = __fmul_rn(vB, kf), fC = __fmul_rn(vC, kf);
        int lo = tbeg - t;          // >0 only in first (misaligned) window
        int hi = tend - t;          // <64 only in last partial window
        if (lo <= 0 && hi >= 64) {
            if (q == 0)            k2_window<false, 1>(fA, fB, fC, s, 0, 64);
            else if (q == NF - 1)  k2_window<false, 2>(fA, fB, fC, s, 0, 64);
            else                   k2_window<false, 0>(fA, fB, fC, s, 0, 64);
        } else {
            k2_window<true, 0>(fA, fB, fC, s, (lo > 0) ? lo : 0, (hi < 64) ? hi : 64);
        }
        vA = vB; vB = vC; vC = vNext;
        t += 64;
    }
    tmod[((size_t)c * NN + n) * NH + h] = fmodf(s, tpi_f());
}

// K3: offsets chain — sequential f32 over chunks, coalesced [c][n][h] layout
__global__ __launch_bounds__(64) void k3_offsets(const float* __restrict__ tmod,
                                                 float* __restrict__ offs) {
    int n = blockIdx.x;
    int h = threadIdx.x;
    float cum = 0.0f;
    for (int c = 0; c < NCHUNK; ++c) {
        offs[((size_t)c * NN + n) * NH + h] = fmodf(cum, tpi_f());
        cum = __fadd_rn(cum, tmod[((size_t)c * NN + n) * NH + h]);
    }
}

// K4 window: full synthesis body. SPAN: chunk boundary at R==rb (s resets to om,
// offset switches off0->off1); compile-time R vs SGPR rb -> cheap cndmask.
template<int SP, bool SPAN>
static __device__ __forceinline__ void k4_window(float fA, float fB, float fC,
                                                 float a0, float a1,
                                                 float& s, float off0r, float off1r, int rb,
                                                 int v, int h, int kb,
                                                 const float2* wtab,
                                                 float (*vsum)[PIECE]) {
    #pragma unroll
    for (int R = 0; R < 64; ++R) {
        float wy = (float)((R < 32) ? (2 * R + 65) : (2 * R - 63)) * 0.0078125f;
        float wx = 1.0f - wy;
        float h0 = (R < 32) ? fA : fB;
        float h1 = (R < 32) ? fB : fC;
        float fe;
        if (SP == 1 && R < 32)       fe = fB;
        else if (SP == 2 && R >= 32) fe = fB;
        else fe = __fadd_rn(__fmul_rn(h0, wx), __fmul_rn(h1, wy));
        float om = __fmul_rn(fe, omc_f());
        if (SPAN) s = (R == rb) ? om : __fadd_rn(s, om);    // cumsum restarts at boundary
        else      s = __fadd_rn(s, om);
        float offr = SPAN ? ((R >= rb) ? off1r : off0r) : off0r;
        float pr = __fmaf_rn(s, inv2pi_f(), offr);
        float fr_, sv;
        asm("v_fract_f32 %0, %1" : "=v"(fr_) : "v"(pr));
        asm("v_sin_f32 %0, %1" : "=v"(sv) : "v"(fr_));      // sin(2pi*frac)
        float2 wab = wtab[R];
        float amp = __fadd_rn(__fmul_rn(a1, wab.x), __fmul_rn(a0, wab.y));
        amp = (fe > 8000.0f) ? 0.0f : amp;
        float ct = wave_sum_to63(__fmul_rn(sv, amp));
        if (h == 63) vsum[v][kb + R] = ct;
    }
}

// K4: synthesis. Block = (b, piece of 128 samples); 512 threads = 8 voices x 64 h.
__global__ __launch_bounds__(512) void k4_synth(const float* __restrict__ freqs,
                                                const float* __restrict__ ha,
                                                const float* __restrict__ substart,
                                                const float* __restrict__ offs,
                                                float* __restrict__ out) {
    int p = blockIdx.x % NPIECE;
    int b = blockIdx.x / NPIECE;
    int tid = threadIdx.x;
    int v = tid >> 6, h = tid & 63;
    int n = (b << 3) + v;

    __shared__ float2 wtab[64];            // {win[r], win[64+r]}
    __shared__ float vsum[NVOICE][PIECE];
    if (tid < 64) {
        float aA = __fmul_rn(tpi_f(), (float)tid) * 0.0078125f;
        float aB = __fmul_rn(tpi_f(), (float)(tid + 64)) * 0.0078125f;
        wtab[tid] = make_float2(0.5f - 0.5f * cosf(aA), 0.5f - 0.5f * cosf(aB));
    }
    __syncthreads();

    const float kf = (float)(h + 1);
    const float* __restrict__ fr  = freqs + n * NF;
    const float* __restrict__ han = ha + ((size_t)n * NH + h) * NF;   // [n][h][f]
    int t0 = p << 7;
    int q  = t0 >> 6;                       // = 2p
    int c0 = t0 / 1000;
    int cL = (t0 + PIECE - 1) / 1000;

    float vA = fr[(q > 0) ? q - 1 : 0];
    float vB = fr[q];
    float vC = fr[(q + 1 < NF) ? q + 1 : NF - 1];
    float vD = fr[(q + 2 < NF) ? q + 2 : NF - 1];
    float a0 = han[q];
    float a1 = han[(q + 1 < NF) ? q + 1 : NF - 1];
    float a2 = han[(q + 2 < NF) ? q + 2 : NF - 1];
    float s     = substart[((size_t)p * NN + n) * NH + h];
    float off0r = __fmul_rn(offs[((size_t)c0 * NN + n) * NH + h], inv2pi_f());

    float fA = __fmul_rn(vA, kf), fB = __fmul_rn(vB, kf);
    float fC = __fmul_rn(vC, kf), fD = __fmul_rn(vD, kf);

    if (c0 == cL) {
        if (q == 0) {
            k4_window<1, false>(fA, fB, fC, a0, a1, s, off0r, off0r, 64, v, h, 0,  wtab, vsum);
            k4_window<0, false>(fB, fC, fD, a1, a2, s, off0r, off0r, 64, v, h, 64, wtab, vsum);
        } else if (q + 1 == NF - 1) {
            k4_window<0, false>(fA, fB, fC, a0, a1, s, off0r, off0r, 64, v, h, 0,  wtab, vsum);
            k4_window<2, false>(fB, fC, fD, a1, a2, s, off0r, off0r, 64, v, h, 64, wtab, vsum);
        } else {
            k4_window<0, false>(fA, fB, fC, a0, a1, s, off0r, off0r, 64, v, h, 0,  wtab, vsum);
            k4_window<0, false>(fB, fC, fD, a1, a2, s, off0r, off0r, 64, v, h, 64, wtab, vsum);
        }
    } else {
        float off1r = __fmul_rn(offs[((size_t)cL * NN + n) * NH + h], inv2pi_f());
        int tb = cL * 1000;                 // boundary sample (s resets there)
        if (tb < t0 + 64) {
            k4_window<0, true >(fA, fB, fC, a0, a1, s, off0r, off1r, tb - t0,      v, h, 0,  wtab, vsum);
            k4_window<0, false>(fB, fC, fD, a1, a2, s, off1r, off1r, 64,           v, h, 64, wtab, vsum);
        } else {
            k4_window<0, false>(fA, fB, fC, a0, a1, s, off0r, off0r, 64,           v, h, 0,  wtab, vsum);
            k4_window<0, true >(fB, fC, fD, a1, a2, s, off0r, off1r, tb - t0 - 64, v, h, 64, wtab, vsum);
        }
    }
    __syncthreads();

    if (tid < PIECE) {
        float acc = 0.0f;
        #pragma unroll
        for (int vv = 0; vv < NVOICE; ++vv) acc = __fadd_rn(acc, vsum[vv][tid]);
        out[(size_t)b * NT + t0 + tid] = __fmul_rn(0.02f, acc);
    }
}

extern "C" void kernel_launch(void* const* d_in, const int* in_sizes, int n_in,
                              void* d_out, int out_size, void* d_ws, size_t ws_size,
                              hipStream_t stream) {
    (void)in_sizes; (void)n_in; (void)out_size; (void)ws_size;
    const float* freqs = (const float*)d_in[0];   // (2,8,500)
    const float* harms = (const float*)d_in[1];   // (2,8,64,500)
    const float* amps  = (const float*)d_in[2];   // (2,8,500)
    float* out = (float*)d_out;                   // (2,32000)

    // Workspace partition (floats): 512000 + 256000 + 32768 + 32768 = 3.3 MB
    float* ws = (float*)d_ws;
    float* ha       = ws;                                    // [n][h][f]
    float* substart = ha + (size_t)NN * NH * NF;             // [piece][n][h]
    float* tmod     = substart + (size_t)NPIECE * NN * NH;   // [c][n][h]
    float* offs     = tmod + (size_t)NCHUNK * NN * NH;       // [c][n][h]

    hipLaunchKernelGGL(k1_harm_amps, dim3(NN * 2), dim3(256), 0, stream,
                       freqs, harms, amps, ha);
    hipLaunchKernelGGL(k2_chunk_scan, dim3(NN * NCHUNK), dim3(64), 0, stream,
                       freqs, substart, tmod);
    hipLaunchKernelGGL(k3_offsets, dim3(NN), dim3(64), 0, stream,
                       tmod, offs);
    hipLaunchKernelGGL(k4_synth, dim3(NB * NPIECE), dim3(512), 0, stream,
                       freqs, ha, substart, offs, out);
}

// Round 5
// 50.063 us; speedup vs baseline: 4.2931x; 1.2419x over previous
//
#include <hip/hip_runtime.h>
#include <math.h>

// Problem geometry (fixed by the reference)
#define NB 2
#define NVOICE 8
#define NN (NB * NVOICE)   // 16 series
#define NH 64              // harmonics
#define NF 500             // frames
#define NT 32000           // samples
#define NCHUNK 32          // angular_cumsum chunks of 1000
#define CHUNK 1000
#define NPIECE 250         // 128-sample output pieces
#define PIECE 128

static __device__ __forceinline__ float tpi_f()    { return (float)(6.283185307179586); }
static __device__ __forceinline__ float omc_f()    { return (float)(6.283185307179586 / 16000.0); }
static __device__ __forceinline__ float inv2pi_f() { return (float)(1.0 / 6.283185307179586); }

// DPP add helper
template<int CTRL>
static __device__ __forceinline__ float dpp_add(float x) {
    int y = __builtin_amdgcn_update_dpp(0, __float_as_int(x), CTRL, 0xF, 0xF, true);
    return x + __int_as_float(y);
}
// Sum within each row of 16 lanes; result on ALL lanes of the row.
static __device__ __forceinline__ float row16_sum(float x) {
    x = dpp_add<0xB1>(x);    // quad_perm xor1
    x = dpp_add<0x4E>(x);    // quad_perm xor2
    x = dpp_add<0x141>(x);   // row_half_mirror (sum over 8)
    x = dpp_add<0x140>(x);   // row_mirror      (sum over 16)
    return x;
}
// Full 64-lane sum broadcast to all lanes (prologue-only; LDS-pipe shuffles ok)
static __device__ __forceinline__ float wave_sum_all(float x) {
    #pragma unroll
    for (int m = 1; m < 64; m <<= 1) x += __shfl_xor(x, m, 64);
    return x;
}

// ---- 64-sample window body for K2: branch-free, per-R constants folded ----
// Window q covers t = 64q + R.  R<32: lerp pair (q-1,q), wy=(2R+65)/128;
// R>=32: pair (q,q+1), wy=(2R-63)/128.  SP=1: q==0; SP=2: q==NF-1.
template<bool MASKED, int SP>
static __device__ __forceinline__ void k2_window(float fA, float fB, float fC,
                                                 float& s, int lo, int hi) {
    #pragma unroll
    for (int R = 0; R < 64; ++R) {
        float wy = (float)((R < 32) ? (2 * R + 65) : (2 * R - 63)) * 0.0078125f;
        float wx = 1.0f - wy;
        float h0 = (R < 32) ? fA : fB;
        float h1 = (R < 32) ? fB : fC;
        float fe;
        if (SP == 1 && R < 32)       fe = fB;
        else if (SP == 2 && R >= 32) fe = fB;
        else fe = __fadd_rn(__fmul_rn(h0, wx), __fmul_rn(h1, wy));
        float om = __fmul_rn(fe, omc_f());
        if (MASKED) om = (R >= lo && R < hi) ? om : 0.0f;   // fadd(s,+0)=s exact
        s = __fadd_rn(s, om);
    }
}

// K2: bit-exact f32 omega scan per (n,c); stores exclusive prefix s at every
// 128-aligned t (piece starts) and the chunk total mod 2pi.
__global__ __launch_bounds__(64) void k2_chunk_scan(const float* __restrict__ freqs,
                                                    float* __restrict__ substart,
                                                    float* __restrict__ tmod) {
    int n = blockIdx.x >> 5, c = blockIdx.x & 31;
    int h = threadIdx.x;
    const float kf = (float)(h + 1);
    const float* __restrict__ fr = freqs + n * NF;
    const int tbeg = c * CHUNK, tend = tbeg + CHUNK;
    int t = tbeg & ~63;
    int q = t >> 6;
    float vA = fr[(q > 0) ? q - 1 : 0];
    float vB = fr[q];
    float vC = fr[(q + 1 < NF) ? q + 1 : NF - 1];
    float s = 0.0f;
    while (t < tend) {
        q = t >> 6;
        float vNext = fr[(q + 2 < NF) ? q + 2 : NF - 1];    // prefetch next window
        if ((t & 127) == 0 && t >= tbeg)
            substart[(((size_t)(t >> 7)) * NN + n) * NH + h] = s;
        float fA = __fmul_rn(vA, kf), fB = __fmul_rn(vB, kf), fC = __fmul_rn(vC, kf);
        int lo = tbeg - t;
        int hi = tend - t;
        if (lo <= 0 && hi >= 64) {
            if (q == 0)            k2_window<false, 1>(fA, fB, fC, s, 0, 64);
            else if (q == NF - 1)  k2_window<false, 2>(fA, fB, fC, s, 0, 64);
            else                   k2_window<false, 0>(fA, fB, fC, s, 0, 64);
        } else {
            k2_window<true, 0>(fA, fB, fC, s, (lo > 0) ? lo : 0, (hi < 64) ? hi : 64);
        }
        vA = vB; vB = vC; vC = vNext;
        t += 64;
    }
    tmod[((size_t)c * NN + n) * NH + h] = fmodf(s, tpi_f());
}

// ---- synthesis slab: 16 samples, fully unrolled, R = R0+Ri compile-time ----
template<int SP, bool SPAN, int R0>
static __device__ __forceinline__ void syn_slab16(float fA, float fB, float fC,
                                                  float a0, float a1,
                                                  float& s, float off0r, float off1r, int rb,
                                                  int v, int h, int kb,
                                                  const float2* wtab,
                                                  float (*vsum4)[4][PIECE]) {
    #pragma unroll
    for (int Ri = 0; Ri < 16; ++Ri) {
        const int R = R0 + Ri;
        float wy = (float)((R < 32) ? (2 * R + 65) : (2 * R - 63)) * 0.0078125f;
        float wx = 1.0f - wy;
        float h0 = (R < 32) ? fA : fB;
        float h1 = (R < 32) ? fB : fC;
        float fe;
        if (SP == 1 && R < 32)       fe = fB;
        else if (SP == 2 && R >= 32) fe = fB;
        else fe = __fadd_rn(__fmul_rn(h0, wx), __fmul_rn(h1, wy));
        float om = __fmul_rn(fe, omc_f());
        if (SPAN) s = (R == rb) ? om : __fadd_rn(s, om);    // cumsum restarts at chunk boundary
        else      s = __fadd_rn(s, om);
        float offr = SPAN ? ((R >= rb) ? off1r : off0r) : off0r;
        float pr = __fmaf_rn(s, inv2pi_f(), offr);
        float fr_, sv;
        asm("v_fract_f32 %0, %1" : "=v"(fr_) : "v"(pr));
        asm("v_sin_f32 %0, %1" : "=v"(sv) : "v"(fr_));      // sin(2pi*frac)
        float2 wab = wtab[R];
        float amp = __fadd_rn(__fmul_rn(a1, wab.x), __fmul_rn(a0, wab.y));
        amp = (fe > 8000.0f) ? 0.0f : amp;
        float ct = row16_sum(__fmul_rn(sv, amp));
        if ((h & 15) == 0) vsum4[v][h >> 4][kb + R] = ct;   // 4 row partials per voice
    }
}

template<int SP, bool SPAN>
static __device__ __forceinline__ void syn_window(float fA, float fB, float fC,
                                                  float a0, float a1,
                                                  float& s, float off0r, float off1r, int rb,
                                                  int v, int h, int kb,
                                                  const float2* wtab,
                                                  float (*vsum4)[4][PIECE]) {
    syn_slab16<SP, SPAN, 0 >(fA, fB, fC, a0, a1, s, off0r, off1r, rb, v, h, kb, wtab, vsum4);
    syn_slab16<SP, SPAN, 16>(fA, fB, fC, a0, a1, s, off0r, off1r, rb, v, h, kb, wtab, vsum4);
    syn_slab16<SP, SPAN, 32>(fA, fB, fC, a0, a1, s, off0r, off1r, rb, v, h, kb, wtab, vsum4);
    syn_slab16<SP, SPAN, 48>(fA, fB, fC, a0, a1, s, off0r, off1r, rb, v, h, kb, wtab, vsum4);
}

// KS: fused normalization + offsets + synthesis. Block = (b, piece of 128).
__global__ __launch_bounds__(512) void ksyn(const float* __restrict__ freqs,
                                            const float* __restrict__ harms,
                                            const float* __restrict__ amps,
                                            const float* __restrict__ substart,
                                            const float* __restrict__ tmod,
                                            float* __restrict__ out) {
    int p = blockIdx.x % NPIECE;
    int b = blockIdx.x / NPIECE;
    int tid = threadIdx.x;
    int v = tid >> 6, h = tid & 63;
    int n = (b << 3) + v;

    __shared__ float2 wtab[64];                 // {win[r], win[64+r]}
    __shared__ float vsum4[NVOICE][4][PIECE];   // row-of-16 partials, 16 KB
    if (tid < 64) {
        float aA = __fmul_rn(tpi_f(), (float)tid) * 0.0078125f;
        float aB = __fmul_rn(tpi_f(), (float)(tid + 64)) * 0.0078125f;
        wtab[tid] = make_float2(0.5f - 0.5f * cosf(aA), 0.5f - 0.5f * cosf(aB));
    }
    __syncthreads();

    const float kf = (float)(h + 1);
    int t0 = p << 7;
    int q  = t0 >> 6;                           // = 2p
    int c0 = t0 / 1000;
    int cL = (t0 + PIECE - 1) / 1000;

    // ---- inline k3: offsets (rev units) for chunks c0 and cL
    const float* __restrict__ tm = tmod + (size_t)n * NH + h;   // [c][n][h]
    float cum = 0.0f;
    for (int c = 0; c < c0; ++c)
        cum = __fadd_rn(cum, tm[(size_t)c * NN * NH]);
    float off0r = __fmul_rn(fmodf(cum, tpi_f()), inv2pi_f());
    float off1r = off0r;
    if (cL != c0) {
        float cum2 = __fadd_rn(cum, tm[(size_t)c0 * NN * NH]);
        off1r = __fmul_rn(fmodf(cum2, tpi_f()), inv2pi_f());
    }

    // ---- inline k1: harmonic amplitudes for frames q, q+1, q+2 (clamped)
    int f1 = (q + 1 < NF) ? q + 1 : NF - 1;
    int f2 = (q + 2 < NF) ? q + 2 : NF - 1;
    const float* __restrict__ hb = harms + ((size_t)n * NH + h) * NF;
    float a0, a1, a2;
    {
        float fq0 = freqs[n * NF + q],  fq1 = freqs[n * NF + f1], fq2 = freqs[n * NF + f2];
        float va0 = amps [n * NF + q],  va1 = amps [n * NF + f1], va2 = amps [n * NF + f2];
        float hm0 = hb[q], hm1 = hb[f1], hm2 = hb[f2];
        hm0 = (__fmul_rn(fq0, kf) > 8000.0f) ? 0.0f : hm0;
        hm1 = (__fmul_rn(fq1, kf) > 8000.0f) ? 0.0f : hm1;
        hm2 = (__fmul_rn(fq2, kf) > 8000.0f) ? 0.0f : hm2;
        float d0 = wave_sum_all(hm0), d1 = wave_sum_all(hm1), d2s = wave_sum_all(hm2);
        d0  = (d0  == 0.0f) ? 1e-7f : d0;
        d1  = (d1  == 0.0f) ? 1e-7f : d1;
        d2s = (d2s == 0.0f) ? 1e-7f : d2s;
        a0 = __fmul_rn(va0, __fdiv_rn(hm0, d0));
        a1 = __fmul_rn(va1, __fdiv_rn(hm1, d1));
        a2 = __fmul_rn(va2, __fdiv_rn(hm2, d2s));
    }

    // ---- freq lerp endpoints (frame-level hf, bit-exact)
    const float* __restrict__ fr = freqs + n * NF;
    float fA = __fmul_rn(fr[(q > 0) ? q - 1 : 0], kf);
    float fB = __fmul_rn(fr[q], kf);
    float fC = __fmul_rn(fr[f1], kf);
    float fD = __fmul_rn(fr[f2], kf);

    float s = substart[((size_t)p * NN + n) * NH + h];

    if (c0 == cL) {
        if (q == 0) {
            syn_window<1, false>(fA, fB, fC, a0, a1, s, off0r, off0r, 64, v, h, 0,  wtab, vsum4);
            syn_window<0, false>(fB, fC, fD, a1, a2, s, off0r, off0r, 64, v, h, 64, wtab, vsum4);
        } else if (q + 1 == NF - 1) {
            syn_window<0, false>(fA, fB, fC, a0, a1, s, off0r, off0r, 64, v, h, 0,  wtab, vsum4);
            syn_window<2, false>(fB, fC, fD, a1, a2, s, off0r, off0r, 64, v, h, 64, wtab, vsum4);
        } else {
            syn_window<0, false>(fA, fB, fC, a0, a1, s, off0r, off0r, 64, v, h, 0,  wtab, vsum4);
            syn_window<0, false>(fB, fC, fD, a1, a2, s, off0r, off0r, 64, v, h, 64, wtab, vsum4);
        }
    } else {
        int tb = cL * 1000;                     // chunk boundary sample (s resets)
        if (tb < t0 + 64) {
            syn_window<0, true >(fA, fB, fC, a0, a1, s, off0r, off1r, tb - t0,      v, h, 0,  wtab, vsum4);
            syn_window<0, false>(fB, fC, fD, a1, a2, s, off1r, off1r, 64,           v, h, 64, wtab, vsum4);
        } else {
            syn_window<0, false>(fA, fB, fC, a0, a1, s, off0r, off0r, 64,           v, h, 0,  wtab, vsum4);
            syn_window<0, true >(fB, fC, fD, a1, a2, s, off0r, off1r, tb - t0 - 64, v, h, 64, wtab, vsum4);
        }
    }
    __syncthreads();

    if (tid < PIECE) {
        float acc = 0.0f;
        #pragma unroll
        for (int vv = 0; vv < NVOICE; ++vv) {
            #pragma unroll
            for (int rr = 0; rr < 4; ++rr)
                acc = __fadd_rn(acc, vsum4[vv][rr][tid]);
        }
        out[(size_t)b * NT + t0 + tid] = __fmul_rn(0.02f, acc);
    }
}

extern "C" void kernel_launch(void* const* d_in, const int* in_sizes, int n_in,
                              void* d_out, int out_size, void* d_ws, size_t ws_size,
                              hipStream_t stream) {
    (void)in_sizes; (void)n_in; (void)out_size; (void)ws_size;
    const float* freqs = (const float*)d_in[0];   // (2,8,500)
    const float* harms = (const float*)d_in[1];   // (2,8,64,500)
    const float* amps  = (const float*)d_in[2];   // (2,8,500)
    float* out = (float*)d_out;                   // (2,32000)

    // Workspace (floats): 256000 + 32768 = ~1.2 MB
    float* ws = (float*)d_ws;
    float* substart = ws;                                    // [piece][n][h]
    float* tmod     = substart + (size_t)NPIECE * NN * NH;   // [c][n][h]

    hipLaunchKernelGGL(k2_chunk_scan, dim3(NN * NCHUNK), dim3(64), 0, stream,
                       freqs, substart, tmod);
    hipLaunchKernelGGL(ksyn, dim3(NB * NPIECE), dim3(512), 0, stream,
                       freqs, harms, amps, substart, tmod, out);
}

// Round 6
// 38.839 us; speedup vs baseline: 5.5339x; 1.2890x over previous
//
#include <hip/hip_runtime.h>
#include <math.h>

// Problem geometry (fixed by the reference)
#define NB 2
#define NVOICE 8
#define NN (NB * NVOICE)   // 16 series
#define NH 64              // harmonics
#define NF 500             // frames
#define NT 32000           // samples
#define NCHUNK 32          // angular_cumsum chunks of 1000
#define CHUNK 1000
#define NWIN 500           // one 64-sample window per synthesis block
#define WIN 64

static __device__ __forceinline__ float tpi_f()    { return (float)(6.283185307179586); }
static __device__ __forceinline__ float omc_f()    { return (float)(6.283185307179586 / 16000.0); }
static __device__ __forceinline__ float inv2pi_f() { return (float)(1.0 / 6.283185307179586); }

// DPP add helper
template<int CTRL>
static __device__ __forceinline__ float dpp_add(float x) {
    int y = __builtin_amdgcn_update_dpp(0, __float_as_int(x), CTRL, 0xF, 0xF, true);
    return x + __int_as_float(y);
}
// Sum within each row of 16 lanes; result on ALL lanes of the row.
static __device__ __forceinline__ float row16_sum(float x) {
    x = dpp_add<0xB1>(x);    // quad_perm xor1
    x = dpp_add<0x4E>(x);    // quad_perm xor2
    x = dpp_add<0x141>(x);   // row_half_mirror (sum over 8)
    x = dpp_add<0x140>(x);   // row_mirror      (sum over 16)
    return x;
}
// Full 64-lane sum broadcast to all lanes (prologue-only)
static __device__ __forceinline__ float wave_sum_all(float x) {
    #pragma unroll
    for (int m = 1; m < 64; m <<= 1) x += __shfl_xor(x, m, 64);
    return x;
}

// ---- 64-sample window body for K2: branch-free, per-R constants folded ----
// Window q covers t = 64q + R.  R<32: lerp pair (q-1,q), wy=(2R+65)/128;
// R>=32: pair (q,q+1), wy=(2R-63)/128.  SP=1: q==0; SP=2: q==NF-1.
template<bool MASKED, int SP>
static __device__ __forceinline__ void k2_window(float fA, float fB, float fC,
                                                 float& s, int lo, int hi) {
    #pragma unroll
    for (int R = 0; R < 64; ++R) {
        float wy = (float)((R < 32) ? (2 * R + 65) : (2 * R - 63)) * 0.0078125f;
        float wx = 1.0f - wy;
        float h0 = (R < 32) ? fA : fB;
        float h1 = (R < 32) ? fB : fC;
        float fe;
        if (SP == 1 && R < 32)       fe = fB;
        else if (SP == 2 && R >= 32) fe = fB;
        else fe = __fadd_rn(__fmul_rn(h0, wx), __fmul_rn(h1, wy));
        float om = __fmul_rn(fe, omc_f());
        if (MASKED) om = (R >= lo && R < hi) ? om : 0.0f;   // fadd(s,+0)=s exact
        s = __fadd_rn(s, om);
    }
}

// K2: bit-exact f32 omega scan per (n,c); stores exclusive prefix s at every
// 64-aligned window start inside the chunk, and the chunk total mod 2pi.
__global__ __launch_bounds__(64) void k2_chunk_scan(const float* __restrict__ freqs,
                                                    float* __restrict__ substart,
                                                    float* __restrict__ tmod) {
    int n = blockIdx.x >> 5, c = blockIdx.x & 31;
    int h = threadIdx.x;
    const float kf = (float)(h + 1);
    const float* __restrict__ fr = freqs + n * NF;
    const int tbeg = c * CHUNK, tend = tbeg + CHUNK;
    int t = tbeg & ~63;
    int q = t >> 6;
    float vA = fr[(q > 0) ? q - 1 : 0];
    float vB = fr[q];
    float vC = fr[(q + 1 < NF) ? q + 1 : NF - 1];
    float s = 0.0f;
    while (t < tend) {
        q = t >> 6;
        float vNext = fr[(q + 2 < NF) ? q + 2 : NF - 1];    // prefetch next window
        if (t >= tbeg)
            substart[(((size_t)q) * NN + n) * NH + h] = s;  // exclusive prefix at window start
        float fA = __fmul_rn(vA, kf), fB = __fmul_rn(vB, kf), fC = __fmul_rn(vC, kf);
        int lo = tbeg - t;
        int hi = tend - t;
        if (lo <= 0 && hi >= 64) {
            if (q == 0)            k2_window<false, 1>(fA, fB, fC, s, 0, 64);
            else if (q == NF - 1)  k2_window<false, 2>(fA, fB, fC, s, 0, 64);
            else                   k2_window<false, 0>(fA, fB, fC, s, 0, 64);
        } else {
            k2_window<true, 0>(fA, fB, fC, s, (lo > 0) ? lo : 0, (hi < 64) ? hi : 64);
        }
        __builtin_amdgcn_sched_barrier(0);
        vA = vB; vB = vC; vC = vNext;
        t += 64;
    }
    tmod[((size_t)c * NN + n) * NH + h] = fmodf(s, tpi_f());
}

// ---- synthesis slab: 16 samples of one window, fully unrolled ----
template<int SP, bool SPAN, int R0>
static __device__ __forceinline__ void syn_slab16(float fA, float fB, float fC,
                                                  float a0, float a1,
                                                  float& s, float off0r, float off1r, int rb,
                                                  int v, int h,
                                                  const float2* wtab,
                                                  float (*vsum4)[4][WIN + 1]) {
    #pragma unroll
    for (int Ri = 0; Ri < 16; ++Ri) {
        const int R = R0 + Ri;
        float wy = (float)((R < 32) ? (2 * R + 65) : (2 * R - 63)) * 0.0078125f;
        float wx = 1.0f - wy;
        float h0 = (R < 32) ? fA : fB;
        float h1 = (R < 32) ? fB : fC;
        float fe;
        if (SP == 1 && R < 32)       fe = fB;
        else if (SP == 2 && R >= 32) fe = fB;
        else fe = __fadd_rn(__fmul_rn(h0, wx), __fmul_rn(h1, wy));
        float om = __fmul_rn(fe, omc_f());
        if (SPAN) s = (R == rb) ? om : __fadd_rn(s, om);    // cumsum restarts at chunk boundary
        else      s = __fadd_rn(s, om);
        float offr = SPAN ? ((R >= rb) ? off1r : off0r) : off0r;
        float pr = __fmaf_rn(s, inv2pi_f(), offr);
        float fr_, sv;
        asm("v_fract_f32 %0, %1" : "=v"(fr_) : "v"(pr));
        asm("v_sin_f32 %0, %1" : "=v"(sv) : "v"(fr_));      // sin(2pi*frac)
        float2 wab = wtab[R];
        float amp = __fadd_rn(__fmul_rn(a1, wab.x), __fmul_rn(a0, wab.y));
        amp = (fe > 8000.0f) ? 0.0f : amp;
        float ct = row16_sum(__fmul_rn(sv, amp));
        if ((h & 15) == 0) vsum4[v][h >> 4][R] = ct;        // 4 row partials per voice
    }
    __builtin_amdgcn_sched_barrier(0);
}

template<int SP, bool SPAN>
static __device__ __forceinline__ void syn_window(float fA, float fB, float fC,
                                                  float a0, float a1,
                                                  float& s, float off0r, float off1r, int rb,
                                                  int v, int h,
                                                  const float2* wtab,
                                                  float (*vsum4)[4][WIN + 1]) {
    syn_slab16<SP, SPAN, 0 >(fA, fB, fC, a0, a1, s, off0r, off1r, rb, v, h, wtab, vsum4);
    syn_slab16<SP, SPAN, 16>(fA, fB, fC, a0, a1, s, off0r, off1r, rb, v, h, wtab, vsum4);
    syn_slab16<SP, SPAN, 32>(fA, fB, fC, a0, a1, s, off0r, off1r, rb, v, h, wtab, vsum4);
    syn_slab16<SP, SPAN, 48>(fA, fB, fC, a0, a1, s, off0r, off1r, rb, v, h, wtab, vsum4);
}

// KS: fused normalization + offsets + synthesis. Block = (b, window q of 64).
__global__ __launch_bounds__(512) void ksyn(const float* __restrict__ freqs,
                                            const float* __restrict__ harms,
                                            const float* __restrict__ amps,
                                            const float* __restrict__ substart,
                                            const float* __restrict__ tmod,
                                            float* __restrict__ out) {
    int q = blockIdx.x % NWIN;
    int b = blockIdx.x / NWIN;
    int tid = threadIdx.x;
    int v = tid >> 6, h = tid & 63;
    int n = (b << 3) + v;

    __shared__ float2 wtab[64];                      // {win[r], win[64+r]}
    __shared__ float vsum4[NVOICE][4][WIN + 1];      // padded: conflict-free partial stores
    if (tid < 64) {
        float aA = __fmul_rn(tpi_f(), (float)tid) * 0.0078125f;
        float aB = __fmul_rn(tpi_f(), (float)(tid + 64)) * 0.0078125f;
        wtab[tid] = make_float2(0.5f - 0.5f * cosf(aA), 0.5f - 0.5f * cosf(aB));
    }
    __syncthreads();

    const float kf = (float)(h + 1);
    int t0 = q << 6;
    int c0 = t0 / 1000;
    int tb = (c0 + 1) * 1000;                        // next chunk boundary
    bool span = (tb < t0 + WIN);                     // boundary strictly inside window

    // ---- inline k3: offsets (rev units) for chunk c0 (and c0+1 if span)
    const float* __restrict__ tm = tmod + (size_t)n * NH + h;   // [c][n][h]
    float cum = 0.0f;
    for (int c = 0; c < c0; ++c)
        cum = __fadd_rn(cum, tm[(size_t)c * NN * NH]);
    float off0r = __fmul_rn(fmodf(cum, tpi_f()), inv2pi_f());
    float off1r = off0r;
    if (span) {
        float cum2 = __fadd_rn(cum, tm[(size_t)c0 * NN * NH]);
        off1r = __fmul_rn(fmodf(cum2, tpi_f()), inv2pi_f());
    }

    // ---- inline k1: harmonic amplitudes for frames q, q+1 (clamped)
    int f1 = (q + 1 < NF) ? q + 1 : NF - 1;
    const float* __restrict__ hb = harms + ((size_t)n * NH + h) * NF;
    float a0, a1;
    {
        float fq0 = freqs[n * NF + q],  fq1 = freqs[n * NF + f1];
        float va0 = amps [n * NF + q],  va1 = amps [n * NF + f1];
        float hm0 = hb[q], hm1 = hb[f1];
        hm0 = (__fmul_rn(fq0, kf) > 8000.0f) ? 0.0f : hm0;
        hm1 = (__fmul_rn(fq1, kf) > 8000.0f) ? 0.0f : hm1;
        float d0 = wave_sum_all(hm0), d1 = wave_sum_all(hm1);
        d0 = (d0 == 0.0f) ? 1e-7f : d0;
        d1 = (d1 == 0.0f) ? 1e-7f : d1;
        a0 = __fmul_rn(va0, __fdiv_rn(hm0, d0));
        a1 = __fmul_rn(va1, __fdiv_rn(hm1, d1));
    }

    // ---- freq lerp endpoints (frame-level hf, bit-exact)
    const float* __restrict__ fr = freqs + n * NF;
    float fA = __fmul_rn(fr[(q > 0) ? q - 1 : 0], kf);
    float fB = __fmul_rn(fr[q], kf);
    float fC = __fmul_rn(fr[f1], kf);

    float s = substart[((size_t)q * NN + n) * NH + h];

    if (!span) {
        if (q == 0)            syn_window<1, false>(fA, fB, fC, a0, a1, s, off0r, off0r, 64, v, h, wtab, vsum4);
        else if (q == NF - 1)  syn_window<2, false>(fA, fB, fC, a0, a1, s, off0r, off0r, 64, v, h, wtab, vsum4);
        else                   syn_window<0, false>(fA, fB, fC, a0, a1, s, off0r, off0r, 64, v, h, wtab, vsum4);
    } else {
        syn_window<0, true>(fA, fB, fC, a0, a1, s, off0r, off1r, tb - t0, v, h, wtab, vsum4);
    }
    __syncthreads();

    if (tid < WIN) {
        float acc = 0.0f;
        #pragma unroll
        for (int vv = 0; vv < NVOICE; ++vv) {
            #pragma unroll
            for (int rr = 0; rr < 4; ++rr)
                acc = __fadd_rn(acc, vsum4[vv][rr][tid]);
        }
        out[(size_t)b * NT + t0 + tid] = __fmul_rn(0.02f, acc);
    }
}

extern "C" void kernel_launch(void* const* d_in, const int* in_sizes, int n_in,
                              void* d_out, int out_size, void* d_ws, size_t ws_size,
                              hipStream_t stream) {
    (void)in_sizes; (void)n_in; (void)out_size; (void)ws_size;
    const float* freqs = (const float*)d_in[0];   // (2,8,500)
    const float* harms = (const float*)d_in[1];   // (2,8,64,500)
    const float* amps  = (const float*)d_in[2];   // (2,8,500)
    float* out = (float*)d_out;                   // (2,32000)

    // Workspace (floats): 500*16*64 + 32*16*64 = 512000 + 32768  (~2.2 MB)
    float* ws = (float*)d_ws;
    float* substart = ws;                                    // [window q][n][h]
    float* tmod     = substart + (size_t)NWIN * NN * NH;     // [c][n][h]

    hipLaunchKernelGGL(k2_chunk_scan, dim3(NN * NCHUNK), dim3(64), 0, stream,
                       freqs, substart, tmod);
    hipLaunchKernelGGL(ksyn, dim3(NB * NWIN), dim3(512), 0, stream,
                       freqs, harms, amps, substart, tmod, out);
}